// Round 3
// baseline (1631.902 us; speedup 1.0000x reference)
//
#include <hip/hip_runtime.h>
#include <hip/hip_bf16.h>
#include <math.h>

using ull = unsigned long long;

// Problem constants
#define ND 4096ull   // n (xd rows)
#define NS 1024ull   // m (s1/s2 rows)
#define DOUT 256ull
#define DIN 768ull
#define NIT 36

// ---- workspace layout (float offsets) ----
constexpr ull O_CXX  = 0;                    // [ND*ND] shared between both divergences
constexpr ull O_CXY  = O_CXX + ND*ND;        // [2][ND*NS]
constexpr ull O_CYX  = O_CXY + 2*ND*NS;      // [2][NS*ND] transposed copies
constexpr ull O_CYY  = O_CYX + 2*ND*NS;      // [2][NS*NS]
constexpr ull O_XD   = O_CYY + 2*NS*NS;      // [ND*DOUT]
constexpr ull O_X1   = O_XD + ND*DOUT;       // [NS*DOUT]
constexpr ull O_X2   = O_X1 + NS*DOUT;       // [NS*DOUT]
constexpr ull O_MT   = O_X2 + NS*DOUT;       // [DOUT*DIN] M transposed (dead after GEMMs)
constexpr ull O_ND_  = O_MT + DOUT*DIN;      // [ND] row norms of xd
constexpr ull O_N1   = O_ND_ + ND;           // [NS]
constexpr ull O_N2   = O_N1 + NS;            // [NS]
constexpr ull O_FAB  = O_N2 + NS;            // [2 div][2 buf][ND]
constexpr ull O_GAB  = O_FAB + 4*ND;         // [2][2][NS]
constexpr ull O_FAA  = O_GAB + 4*NS;         // [2][2][ND]
constexpr ull O_GBB  = O_FAA + 4*ND;         // [2][2][NS]
constexpr ull O_FABN = O_GBB + 4*NS;         // [2][ND] final extrapolation
constexpr ull O_GABN = O_FABN + 2*ND;        // [2][NS]
constexpr ull O_FAAN = O_GABN + 2*NS;        // [2][ND]
constexpr ull O_GBBN = O_FAAN + 2*ND;        // [2][NS]
constexpr ull O_EPS  = O_GBBN + 2*NS;        // [2][NIT]
constexpr ull O_DIST = O_EPS + 2*NIT;        // [2]
constexpr ull WS_FLOATS = O_DIST + 2;
// diameter partials reuse the dead Mt region (runs after all GEMMs)
constexpr ull O_PMIN = O_MT;                 // [96*256]
constexpr ull O_PMAX = O_MT + 96*256;        // [96*256]

constexpr float LOG2E = 1.4426950408889634f;
constexpr float LN2   = 0.69314718055994531f;
constexpr float A_LOG2 = -12.0f;   // -log2(4096)
constexpr float B_LOG2 = -10.0f;   // -log2(1024)

__device__ __forceinline__ float wave_max(float v) {
    #pragma unroll
    for (int o = 32; o; o >>= 1) v = fmaxf(v, __shfl_xor(v, o));
    return v;
}
__device__ __forceinline__ float wave_sum(float v) {
    #pragma unroll
    for (int o = 32; o; o >>= 1) v += __shfl_xor(v, o);
    return v;
}

// ---- transpose M [DIN x DOUT] -> Mt [DOUT x DIN] ----
__global__ __launch_bounds__(256)
void transpose_M_k(const float* __restrict__ M, float* __restrict__ Mt)
{
    int idx = blockIdx.x * 256 + threadIdx.x;
    int r = idx >> 8;
    int c = idx & 255;
    Mt[(size_t)c * DIN + r] = M[idx];
}

// ---- projection GEMM: P = A[MxK] @ B[NxK]^T (64x64 tile, 4x4/thread) ----
__global__ __launch_bounds__(256)
void gemm_proj(const float* __restrict__ A, const float* __restrict__ B,
               float* __restrict__ C, int M, int N, int K)
{
    __shared__ __align__(16) float As[16][68];
    __shared__ __align__(16) float Bs[16][68];
    const int m0 = blockIdx.y * 64, n0 = blockIdx.x * 64;
    const int t = threadIdx.x;
    const int lk = t & 15, lr = t >> 4;
    const int tm = t >> 4, tn = t & 15;
    float acc[4][4] = {};
    for (int k0 = 0; k0 < K; k0 += 16) {
        #pragma unroll
        for (int r = 0; r < 4; r++) {
            As[lk][lr + r*16] = A[(size_t)(m0 + lr + r*16) * K + (k0 + lk)];
            Bs[lk][lr + r*16] = B[(size_t)(n0 + lr + r*16) * K + (k0 + lk)];
        }
        __syncthreads();
        #pragma unroll
        for (int k = 0; k < 16; k++) {
            const float4 a4 = *(const float4*)&As[k][tm*4];
            const float4 b4 = *(const float4*)&Bs[k][tn*4];
            const float av[4] = {a4.x, a4.y, a4.z, a4.w};
            const float bv[4] = {b4.x, b4.y, b4.z, b4.w};
            #pragma unroll
            for (int i = 0; i < 4; i++)
                #pragma unroll
                for (int j = 0; j < 4; j++)
                    acc[i][j] = fmaf(av[i], bv[j], acc[i][j]);
        }
        __syncthreads();
    }
    #pragma unroll
    for (int i = 0; i < 4; i++)
        #pragma unroll
        for (int j = 0; j < 4; j++)
            C[(size_t)(m0 + tm*4 + i) * N + (n0 + tn*4 + j)] = acc[i][j];
}

// ---- cost GEMM: 128x128 tile, 8x8 micro-tile, XOR-swizzled LDS ----
// C[i][j] = 0.5*max(na[i]+nb[j]-2*(A_i . B_j), 0); optional transposed copy CT.
__device__ __forceinline__ int swz4(int row) { return (((row >> 3) ^ row) & 3) << 2; }

__global__ __launch_bounds__(256)
void gemm_cost(const float* __restrict__ A, const float* __restrict__ B,
               float* __restrict__ C, float* __restrict__ CT,
               const float* __restrict__ na, const float* __restrict__ nb,
               int M, int N, int K)
{
    __shared__ __align__(16) float As[128*20];
    __shared__ __align__(16) float Bs[128*20];
    const int t = threadIdx.x;
    const int m0 = blockIdx.y * 128, n0 = blockIdx.x * 128;
    const int tm = t >> 4, tn = t & 15;
    const int srow = t >> 2, skc = (t & 3) << 2;
    float acc[8][8] = {};
    for (int k0 = 0; k0 < K; k0 += 16) {
        #pragma unroll
        for (int s = 0; s < 2; s++) {
            const int row = srow + s * 64;
            const float4 av = *(const float4*)&A[(size_t)(m0 + row) * K + k0 + skc];
            const float4 bv = *(const float4*)&B[(size_t)(n0 + row) * K + k0 + skc];
            *(float4*)&As[row * 20 + (skc ^ swz4(row))] = av;
            *(float4*)&Bs[row * 20 + (skc ^ swz4(row))] = bv;
        }
        __syncthreads();
        #pragma unroll
        for (int k4 = 0; k4 < 4; k4++) {
            float4 a4[8], b4[8];
            #pragma unroll
            for (int i = 0; i < 8; i++) {
                const int r = tm * 8 + i;
                a4[i] = *(const float4*)&As[r * 20 + ((k4 << 2) ^ swz4(r))];
            }
            #pragma unroll
            for (int j = 0; j < 8; j++) {
                const int r = tn * 8 + j;
                b4[j] = *(const float4*)&Bs[r * 20 + ((k4 << 2) ^ swz4(r))];
            }
            #pragma unroll
            for (int i = 0; i < 8; i++)
                #pragma unroll
                for (int j = 0; j < 8; j++) {
                    acc[i][j] = fmaf(a4[i].x, b4[j].x, acc[i][j]);
                    acc[i][j] = fmaf(a4[i].y, b4[j].y, acc[i][j]);
                    acc[i][j] = fmaf(a4[i].z, b4[j].z, acc[i][j]);
                    acc[i][j] = fmaf(a4[i].w, b4[j].w, acc[i][j]);
                }
        }
        __syncthreads();
    }
    float nai[8], nbj[8];
    #pragma unroll
    for (int i = 0; i < 8; i++) nai[i] = na[m0 + tm * 8 + i];
    #pragma unroll
    for (int j = 0; j < 8; j++) nbj[j] = nb[n0 + tn * 8 + j];
    #pragma unroll
    for (int i = 0; i < 8; i++)
        #pragma unroll
        for (int j = 0; j < 8; j++)
            acc[i][j] = 0.5f * fmaxf(nai[i] + nbj[j] - 2.0f * acc[i][j], 0.0f);
    #pragma unroll
    for (int i = 0; i < 8; i++) {
        const float4 lo = {acc[i][0], acc[i][1], acc[i][2], acc[i][3]};
        const float4 hi = {acc[i][4], acc[i][5], acc[i][6], acc[i][7]};
        *(float4*)&C[(size_t)(m0 + tm * 8 + i) * N + n0 + tn * 8]     = lo;
        *(float4*)&C[(size_t)(m0 + tm * 8 + i) * N + n0 + tn * 8 + 4] = hi;
    }
    if (CT) {   // in-register transpose, 32B contiguous per thread-row
        #pragma unroll
        for (int j = 0; j < 8; j++) {
            const float4 lo = {acc[0][j], acc[1][j], acc[2][j], acc[3][j]};
            const float4 hi = {acc[4][j], acc[5][j], acc[6][j], acc[7][j]};
            *(float4*)&CT[(size_t)(n0 + tn * 8 + j) * M + m0 + tm * 8]     = lo;
            *(float4*)&CT[(size_t)(n0 + tn * 8 + j) * M + m0 + tm * 8 + 4] = hi;
        }
    }
}

// ---- row squared-norms (D=256 == blockDim) ----
__global__ __launch_bounds__(256)
void row_norm(const float* __restrict__ x, float* __restrict__ o)
{
    const int i = blockIdx.x;
    const float v = x[(size_t)i * DOUT + threadIdx.x];
    float s = wave_sum(v * v);
    __shared__ float red[4];
    const int wid = threadIdx.x >> 6, lane = threadIdx.x & 63;
    if (lane == 0) red[wid] = s;
    __syncthreads();
    if (threadIdx.x == 0) o[i] = red[0] + red[1] + red[2] + red[3];
}

// ---- stage 1: per-column min/max partials ----
__global__ __launch_bounds__(256)
void colminmax_k(const float* __restrict__ xd, const float* __restrict__ x1,
                 const float* __restrict__ x2, float* __restrict__ ws)
{
    const int b = blockIdx.x, c = threadIdx.x;
    const float* src; int r0;
    if (b < 64)      { src = xd; r0 = b * 64; }
    else if (b < 80) { src = x1; r0 = (b - 64) * 64; }
    else             { src = x2; r0 = (b - 80) * 64; }
    float mn = 3.4e38f, mx = -3.4e38f;
    for (int r = 0; r < 64; r++) {
        const float v = src[(size_t)(r0 + r) * DOUT + c];
        mn = fminf(mn, v); mx = fmaxf(mx, v);
    }
    ws[O_PMIN + (ull)b * 256 + c] = mn;
    ws[O_PMAX + (ull)b * 256 + c] = mx;
}

// ---- stage 2: reduce partials -> diam -> eps schedule ----
__global__ __launch_bounds__(256)
void eps_k(float* __restrict__ ws)
{
    const int c = threadIdx.x;
    const float* pmin = ws + O_PMIN;
    const float* pmax = ws + O_PMAX;
    float mnd = 3.4e38f, mxd = -3.4e38f;
    float mn1 = 3.4e38f, mx1 = -3.4e38f;
    float mn2 = 3.4e38f, mx2 = -3.4e38f;
    for (int b = 0;  b < 64; b++) { mnd = fminf(mnd, pmin[b*256+c]); mxd = fmaxf(mxd, pmax[b*256+c]); }
    for (int b = 64; b < 80; b++) { mn1 = fminf(mn1, pmin[b*256+c]); mx1 = fmaxf(mx1, pmax[b*256+c]); }
    for (int b = 80; b < 96; b++) { mn2 = fminf(mn2, pmin[b*256+c]); mx2 = fmaxf(mx2, pmax[b*256+c]); }
    const float d1 = fmaxf(mxd, mx1) - fminf(mnd, mn1);
    const float d2 = fmaxf(mxd, mx2) - fminf(mnd, mn2);
    float s1 = wave_sum(d1 * d1);
    float s2 = wave_sum(d2 * d2);
    __shared__ float r1[4], r2[4];
    const int wid = c >> 6, lane = c & 63;
    if (lane == 0) { r1[wid] = s1; r2[wid] = s2; }
    __syncthreads();
    if (c < 2 * NIT) {
        const int div = c / NIT, tt = c % NIT;
        const float ss = div ? (r2[0]+r2[1]+r2[2]+r2[3]) : (r1[0]+r1[1]+r1[2]+r1[3]);
        const float diam = sqrtf(ss) + 1e-6f;
        const float sc = fmaxf(0.5f, diam * powf(0.8f, (float)tt));
        ws[O_EPS + (ull)div * NIT + tt] = sc * sc;
    }
}

// ---- per-row stable softmin (exp2-scaled, float4 loads) ----
template<int NV>   // float4 chunks per thread (LEN = NV*1024)
__device__ __forceinline__ void softmin_single(
    const float* __restrict__ Crow, const float* __restrict__ hvec,
    float hc2, float eps,
    const float* __restrict__ selfv, float* __restrict__ outp,
    int row, int phase, float* red)
{
    const int tix = threadIdx.x;
    const float ie2 = LOG2E / eps;
    const float4* C4 = (const float4*)Crow;
    const float4* H4 = (const float4*)hvec;
    float4 v[NV];
    #pragma unroll
    for (int n = 0; n < NV; n++) {
        const float4 c = C4[tix + n * 256];
        if (hvec) {
            const float4 h = H4[tix + n * 256];
            v[n].x = fmaf(h.x - c.x, ie2, hc2);
            v[n].y = fmaf(h.y - c.y, ie2, hc2);
            v[n].z = fmaf(h.z - c.z, ie2, hc2);
            v[n].w = fmaf(h.w - c.w, ie2, hc2);
        } else {
            v[n].x = fmaf(-c.x, ie2, hc2);
            v[n].y = fmaf(-c.y, ie2, hc2);
            v[n].z = fmaf(-c.z, ie2, hc2);
            v[n].w = fmaf(-c.w, ie2, hc2);
        }
    }
    float m = -3.4e38f;
    #pragma unroll
    for (int n = 0; n < NV; n++)
        m = fmaxf(m, fmaxf(fmaxf(v[n].x, v[n].y), fmaxf(v[n].z, v[n].w)));
    m = wave_max(m);
    const int wid = tix >> 6, lane = tix & 63;
    if (lane == 0) red[wid] = m;
    __syncthreads();
    m = fmaxf(fmaxf(red[0], red[1]), fmaxf(red[2], red[3]));
    float s = 0.0f;
    #pragma unroll
    for (int n = 0; n < NV; n++)
        s += exp2f(v[n].x - m) + exp2f(v[n].y - m) + exp2f(v[n].z - m) + exp2f(v[n].w - m);
    s = wave_sum(s);
    __syncthreads();
    if (lane == 0) red[wid] = s;
    __syncthreads();
    if (tix == 0) {
        const float tot = red[0] + red[1] + red[2] + red[3];
        float res = -eps * LN2 * (m + log2f(tot));
        if (phase == 1) res = 0.5f * (selfv[row] + res);
        outp[row] = res;
    }
}

// ---- fused f_aa softmin: one C_xx row pass, both divergences ----
__device__ __forceinline__ void softmin_faa(
    const float* __restrict__ Crow,
    const float* __restrict__ h0, const float* __restrict__ h1,
    float eps0, float eps1,
    const float* __restrict__ self0, const float* __restrict__ self1,
    float* __restrict__ out0, float* __restrict__ out1,
    int row, int phase, float* red)
{
    const int tix = threadIdx.x;
    const float ie0 = LOG2E / eps0;
    const float ie1 = LOG2E / eps1;
    const float4* C4 = (const float4*)Crow;
    const float4* H04 = (const float4*)h0;
    const float4* H14 = (const float4*)h1;
    float4 v0[4], v1[4];
    #pragma unroll
    for (int n = 0; n < 4; n++) {
        const float4 c = C4[tix + n * 256];
        if (phase) {
            const float4 a = H04[tix + n * 256];
            const float4 b = H14[tix + n * 256];
            v0[n].x = fmaf(a.x - c.x, ie0, A_LOG2);
            v0[n].y = fmaf(a.y - c.y, ie0, A_LOG2);
            v0[n].z = fmaf(a.z - c.z, ie0, A_LOG2);
            v0[n].w = fmaf(a.w - c.w, ie0, A_LOG2);
            v1[n].x = fmaf(b.x - c.x, ie1, A_LOG2);
            v1[n].y = fmaf(b.y - c.y, ie1, A_LOG2);
            v1[n].z = fmaf(b.z - c.z, ie1, A_LOG2);
            v1[n].w = fmaf(b.w - c.w, ie1, A_LOG2);
        } else {
            v0[n].x = fmaf(-c.x, ie0, A_LOG2);
            v0[n].y = fmaf(-c.y, ie0, A_LOG2);
            v0[n].z = fmaf(-c.z, ie0, A_LOG2);
            v0[n].w = fmaf(-c.w, ie0, A_LOG2);
            v1[n].x = fmaf(-c.x, ie1, A_LOG2);
            v1[n].y = fmaf(-c.y, ie1, A_LOG2);
            v1[n].z = fmaf(-c.z, ie1, A_LOG2);
            v1[n].w = fmaf(-c.w, ie1, A_LOG2);
        }
    }
    float m0 = -3.4e38f, m1 = -3.4e38f;
    #pragma unroll
    for (int n = 0; n < 4; n++) {
        m0 = fmaxf(m0, fmaxf(fmaxf(v0[n].x, v0[n].y), fmaxf(v0[n].z, v0[n].w)));
        m1 = fmaxf(m1, fmaxf(fmaxf(v1[n].x, v1[n].y), fmaxf(v1[n].z, v1[n].w)));
    }
    m0 = wave_max(m0); m1 = wave_max(m1);
    const int wid = tix >> 6, lane = tix & 63;
    if (lane == 0) { red[wid] = m0; red[4 + wid] = m1; }
    __syncthreads();
    m0 = fmaxf(fmaxf(red[0], red[1]), fmaxf(red[2], red[3]));
    m1 = fmaxf(fmaxf(red[4], red[5]), fmaxf(red[6], red[7]));
    float s0 = 0.0f, s1 = 0.0f;
    #pragma unroll
    for (int n = 0; n < 4; n++) {
        s0 += exp2f(v0[n].x - m0) + exp2f(v0[n].y - m0) + exp2f(v0[n].z - m0) + exp2f(v0[n].w - m0);
        s1 += exp2f(v1[n].x - m1) + exp2f(v1[n].y - m1) + exp2f(v1[n].z - m1) + exp2f(v1[n].w - m1);
    }
    s0 = wave_sum(s0); s1 = wave_sum(s1);
    __syncthreads();
    if (lane == 0) { red[wid] = s0; red[4 + wid] = s1; }
    __syncthreads();
    if (tix == 0) {
        const float t0 = red[0] + red[1] + red[2] + red[3];
        const float t1 = red[4] + red[5] + red[6] + red[7];
        float r0 = -eps0 * LN2 * (m0 + log2f(t0));
        float r1 = -eps1 * LN2 * (m1 + log2f(t1));
        if (phase == 1) { r0 = 0.5f * (self0[row] + r0); r1 = 0.5f * (self1[row] + r1); }
        out0[row] = r0; out1[row] = r1;
    }
}

// ---- fused Sinkhorn step ----
// block map (16384 blocks):
//  [0,8192)      ft   (C_xy rows, len 1024), div = b>>12
//  [8192,10240)  gt   (C_yx rows, len 4096), div = (b-8192)>>10
//  [10240,14336) f_aa (C_xx rows, len 4096), BOTH divergences fused
//  [14336,16384) g_bb (C_yy rows, len 1024), div = (b-14336)>>10
__global__ __launch_bounds__(256)
void sinkhorn_phase(float* __restrict__ ws, int phase, int t)
{
    __shared__ float red[8];
    int b = blockIdx.x;
    int rb, wb;
    if (phase == 0) { rb = 0; wb = 0; }
    else { rb = t & 1; wb = rb ^ 1; }   // phase 2 passes t=36 -> rb=0

    if (b < 8192) {                       // ft -> f_ab
        const int div = b >> 12, i = b & 4095;
        const float eps = (phase == 2) ? 0.25f : ws[O_EPS + (ull)div * NIT + t];
        const float* Crow = ws + O_CXY + (ull)div * ND * NS + (ull)i * NS;
        const float* gab_r = ws + O_GAB + ((ull)div * 2 + rb) * NS;
        const float* fab_r = ws + O_FAB + ((ull)div * 2 + rb) * ND;
        float* outp = (phase == 2) ? (ws + O_FABN + (ull)div * ND)
                                   : (ws + O_FAB + ((ull)div * 2 + wb) * ND);
        softmin_single<1>(Crow, phase ? gab_r : nullptr, B_LOG2, eps, fab_r, outp, i, phase, red);
    } else if (b < 10240) {               // gt -> g_ab
        const int q = b - 8192;
        const int div = q >> 10, j = q & 1023;
        const float eps = (phase == 2) ? 0.25f : ws[O_EPS + (ull)div * NIT + t];
        const float* Crow = ws + O_CYX + (ull)div * ND * NS + (ull)j * ND;
        const float* fab_r = ws + O_FAB + ((ull)div * 2 + rb) * ND;
        const float* gab_r = ws + O_GAB + ((ull)div * 2 + rb) * NS;
        float* outp = (phase == 2) ? (ws + O_GABN + (ull)div * NS)
                                   : (ws + O_GAB + ((ull)div * 2 + wb) * NS);
        softmin_single<4>(Crow, phase ? fab_r : nullptr, A_LOG2, eps, gab_r, outp, j, phase, red);
    } else if (b < 14336) {               // f_aa, both divergences
        const int i = b - 10240;
        const float eps0 = (phase == 2) ? 0.25f : ws[O_EPS + t];
        const float eps1 = (phase == 2) ? 0.25f : ws[O_EPS + NIT + t];
        const float* Crow = ws + O_CXX + (ull)i * ND;
        const float* faa_r0 = ws + O_FAA + (ull)rb * ND;
        const float* faa_r1 = ws + O_FAA + (2ull + rb) * ND;
        float* out0 = (phase == 2) ? (ws + O_FAAN)      : (ws + O_FAA + (ull)wb * ND);
        float* out1 = (phase == 2) ? (ws + O_FAAN + ND) : (ws + O_FAA + (2ull + wb) * ND);
        softmin_faa(Crow, phase ? faa_r0 : nullptr, phase ? faa_r1 : nullptr,
                    eps0, eps1, faa_r0, faa_r1, out0, out1, i, phase, red);
    } else {                              // g_bb
        const int q = b - 14336;
        const int div = q >> 10, i = q & 1023;
        const float eps = (phase == 2) ? 0.25f : ws[O_EPS + (ull)div * NIT + t];
        const float* Crow = ws + O_CYY + (ull)div * NS * NS + (ull)i * NS;
        const float* gbb_r = ws + O_GBB + ((ull)div * 2 + rb) * NS;
        float* outp = (phase == 2) ? (ws + O_GBBN + (ull)div * NS)
                                   : (ws + O_GBB + ((ull)div * 2 + wb) * NS);
        softmin_single<1>(Crow, phase ? gbb_r : nullptr, B_LOG2, eps, gbb_r, outp, i, phase, red);
    }
}

// ---- dist[d] = mean(f_ab_n - f_aa_n) + mean(g_ab_n - g_bb_n) ----
__global__ __launch_bounds__(256)
void reduce_dist(float* __restrict__ ws)
{
    const int d = blockIdx.x;
    const int tix = threadIdx.x;
    float s = 0.0f;
    #pragma unroll
    for (int k = 0; k < 16; k++) {
        const int i = tix + k * 256;
        s += (ws[O_FABN + (ull)d * ND + i] - ws[O_FAAN + (ull)d * ND + i]) * (1.0f / 4096.0f);
    }
    #pragma unroll
    for (int k = 0; k < 4; k++) {
        const int j = tix + k * 256;
        s += (ws[O_GABN + (ull)d * NS + j] - ws[O_GBBN + (ull)d * NS + j]) * (1.0f / 1024.0f);
    }
    s = wave_sum(s);
    __shared__ float red[4];
    const int wid = tix >> 6, lane = tix & 63;
    if (lane == 0) red[wid] = s;
    __syncthreads();
    if (tix == 0) ws[O_DIST + d] = red[0] + red[1] + red[2] + red[3];
}

__global__ void finalize_k(const float* __restrict__ ws, float* __restrict__ out)
{
    const float x = ws[O_DIST + 1] - ws[O_DIST + 0];   // dist2 - dist1
    out[0] = 1.0f / (1.0f + expf(-x));
}

extern "C" void kernel_launch(void* const* d_in, const int* in_sizes, int n_in,
                              void* d_out, int out_size, void* d_ws, size_t ws_size,
                              hipStream_t stream)
{
    if (ws_size < WS_FLOATS * sizeof(float)) return;   // ~150 MB required

    const float* dmat = (const float*)d_in[0];
    const float* s1   = (const float*)d_in[1];
    const float* s2   = (const float*)d_in[2];
    const float* M    = (const float*)d_in[3];
    float* ws  = (float*)d_ws;
    float* out = (float*)d_out;

    float* Mt = ws + O_MT;
    float* xd = ws + O_XD;
    float* x1 = ws + O_X1;
    float* x2 = ws + O_X2;

    transpose_M_k<<<768, 256, 0, stream>>>(M, Mt);
    // projections: X = In @ M  ==  In @ Mt^T
    gemm_proj<<<dim3(4, 64), 256, 0, stream>>>(dmat, Mt, xd, 4096, 256, 768);
    gemm_proj<<<dim3(4, 16), 256, 0, stream>>>(s1,   Mt, x1, 1024, 256, 768);
    gemm_proj<<<dim3(4, 16), 256, 0, stream>>>(s2,   Mt, x2, 1024, 256, 768);
    row_norm<<<4096, 256, 0, stream>>>(xd, ws + O_ND_);
    row_norm<<<1024, 256, 0, stream>>>(x1, ws + O_N1);
    row_norm<<<1024, 256, 0, stream>>>(x2, ws + O_N2);
    // cost matrices (128x128-tile GEMM)
    gemm_cost<<<dim3(32, 32), 256, 0, stream>>>(xd, xd, ws + O_CXX, nullptr, ws + O_ND_, ws + O_ND_, 4096, 4096, 256);
    gemm_cost<<<dim3(8, 32),  256, 0, stream>>>(xd, x1, ws + O_CXY,         ws + O_CYX,         ws + O_ND_, ws + O_N1, 4096, 1024, 256);
    gemm_cost<<<dim3(8, 8),   256, 0, stream>>>(x1, x1, ws + O_CYY,         nullptr,            ws + O_N1,  ws + O_N1, 1024, 1024, 256);
    gemm_cost<<<dim3(8, 32),  256, 0, stream>>>(xd, x2, ws + O_CXY + ND*NS, ws + O_CYX + ND*NS, ws + O_ND_, ws + O_N2, 4096, 1024, 256);
    gemm_cost<<<dim3(8, 8),   256, 0, stream>>>(x2, x2, ws + O_CYY + NS*NS, nullptr,            ws + O_N2,  ws + O_N2, 1024, 1024, 256);
    // diameter + eps schedule (partials overwrite dead Mt region)
    colminmax_k<<<96, 256, 0, stream>>>(xd, x1, x2, ws);
    eps_k<<<1, 256, 0, stream>>>(ws);
    // Sinkhorn loop
    sinkhorn_phase<<<16384, 256, 0, stream>>>(ws, 0, 0);
    for (int t = 0; t < NIT; t++)
        sinkhorn_phase<<<16384, 256, 0, stream>>>(ws, 1, t);
    sinkhorn_phase<<<16384, 256, 0, stream>>>(ws, 2, 36);
    reduce_dist<<<2, 256, 0, stream>>>(ws);
    finalize_k<<<1, 1, 0, stream>>>(ws, out);
}

// Round 4
// 1547.127 us; speedup vs baseline: 1.0548x; 1.0548x over previous
//
#include <hip/hip_runtime.h>
#include <hip/hip_bf16.h>
#include <math.h>

using ull = unsigned long long;
typedef unsigned short u16x8 __attribute__((ext_vector_type(8)));
typedef unsigned short u16x4 __attribute__((ext_vector_type(4)));

// Problem constants
#define ND 4096ull   // n (xd rows)
#define NS 1024ull   // m (s1/s2 rows)
#define DOUT 256ull
#define DIN 768ull
#define NIT 36

// ---- u16 cost-matrix regions (ushort offsets into ws) ----
constexpr ull U_CXX = 0;                 // [ND*ND], shared by both divergences
constexpr ull U_CXY = U_CXX + ND*ND;     // [2][ND*NS]
constexpr ull U_CYX = U_CXY + 2*ND*NS;   // [2][NS*ND] transposed copies
constexpr ull U_CYY = U_CYX + 2*ND*NS;   // [2][NS*NS]
constexpr ull U_TOT = U_CYY + 2*NS*NS;   // 35,651,584 ushorts = ~71.3 MB

// ---- fp32 region (float offsets into ws) ----
constexpr ull O_XD   = U_TOT / 2;
constexpr ull O_X1   = O_XD + ND*DOUT;
constexpr ull O_X2   = O_X1 + NS*DOUT;
constexpr ull O_MT   = O_X2 + NS*DOUT;       // [DOUT*DIN], dead after proj GEMMs
constexpr ull O_ND_  = O_MT + DOUT*DIN;
constexpr ull O_N1   = O_ND_ + ND;
constexpr ull O_N2   = O_N1 + NS;
constexpr ull O_FAB  = O_N2 + NS;            // [2 div][2 buf][ND]
constexpr ull O_GAB  = O_FAB + 4*ND;         // [2][2][NS]
constexpr ull O_FAA  = O_GAB + 4*NS;         // [2][2][ND]
constexpr ull O_GBB  = O_FAA + 4*ND;         // [2][2][NS]
constexpr ull O_FABN = O_GBB + 4*NS;         // [2][ND]
constexpr ull O_GABN = O_FABN + 2*ND;        // [2][NS]
constexpr ull O_FAAN = O_GABN + 2*NS;        // [2][ND]
constexpr ull O_GBBN = O_FAAN + 2*ND;        // [2][NS]
constexpr ull O_EPS  = O_GBBN + 2*NS;        // [2][NIT]
constexpr ull O_QS   = O_EPS + 2*NIT;        // [0]=quant scale s, [1]=dequant qs
constexpr ull O_DIST = O_QS + 2;             // [2]
constexpr ull WS_FLOATS = O_DIST + 2;        // ~19.2M floats -> ~77 MB total
// diameter partials reuse dead Mt region (runs after proj GEMMs)
constexpr ull O_PMIN = O_MT;                 // [96*256]
constexpr ull O_PMAX = O_MT + 96*256;        // [96*256]

constexpr float LOG2E = 1.4426950408889634f;
constexpr float LN2   = 0.69314718055994531f;
constexpr float A_LOG2 = -12.0f;   // -log2(4096)
constexpr float B_LOG2 = -10.0f;   // -log2(1024)

__device__ __forceinline__ float wave_max(float v) {
    #pragma unroll
    for (int o = 32; o; o >>= 1) v = fmaxf(v, __shfl_xor(v, o));
    return v;
}
__device__ __forceinline__ float wave_sum(float v) {
    #pragma unroll
    for (int o = 32; o; o >>= 1) v += __shfl_xor(v, o);
    return v;
}

// ---- transpose M [DIN x DOUT] -> Mt [DOUT x DIN] ----
__global__ __launch_bounds__(256)
void transpose_M_k(const float* __restrict__ M, float* __restrict__ Mt)
{
    int idx = blockIdx.x * 256 + threadIdx.x;
    int r = idx >> 8;
    int c = idx & 255;
    Mt[(size_t)c * DIN + r] = M[idx];
}

// ---- projection GEMM: P = A[MxK] @ B[NxK]^T (64x64 tile, 4x4/thread) ----
__global__ __launch_bounds__(256)
void gemm_proj(const float* __restrict__ A, const float* __restrict__ B,
               float* __restrict__ C, int M, int N, int K)
{
    __shared__ __align__(16) float As[16][68];
    __shared__ __align__(16) float Bs[16][68];
    const int m0 = blockIdx.y * 64, n0 = blockIdx.x * 64;
    const int t = threadIdx.x;
    const int lk = t & 15, lr = t >> 4;
    const int tm = t >> 4, tn = t & 15;
    float acc[4][4] = {};
    for (int k0 = 0; k0 < K; k0 += 16) {
        #pragma unroll
        for (int r = 0; r < 4; r++) {
            As[lk][lr + r*16] = A[(size_t)(m0 + lr + r*16) * K + (k0 + lk)];
            Bs[lk][lr + r*16] = B[(size_t)(n0 + lr + r*16) * K + (k0 + lk)];
        }
        __syncthreads();
        #pragma unroll
        for (int k = 0; k < 16; k++) {
            const float4 a4 = *(const float4*)&As[k][tm*4];
            const float4 b4 = *(const float4*)&Bs[k][tn*4];
            const float av[4] = {a4.x, a4.y, a4.z, a4.w};
            const float bv[4] = {b4.x, b4.y, b4.z, b4.w};
            #pragma unroll
            for (int i = 0; i < 4; i++)
                #pragma unroll
                for (int j = 0; j < 4; j++)
                    acc[i][j] = fmaf(av[i], bv[j], acc[i][j]);
        }
        __syncthreads();
    }
    #pragma unroll
    for (int i = 0; i < 4; i++)
        #pragma unroll
        for (int j = 0; j < 4; j++)
            C[(size_t)(m0 + tm*4 + i) * N + (n0 + tn*4 + j)] = acc[i][j];
}

// ---- cost GEMM (round-2 proven 64x64 structure), u16-quantized outputs ----
// C[i][j] = quant(0.5*max(na[i]+nb[j]-2*(A_i.B_j),0)); optional transposed CT.
__device__ __forceinline__ unsigned int quant16(float c, float s) {
    return __float2uint_rn(fminf(c * s, 65535.0f));
}

__global__ __launch_bounds__(256)
void gemm_cost(const float* __restrict__ A, const float* __restrict__ B,
               unsigned short* __restrict__ C, unsigned short* __restrict__ CT,
               const float* __restrict__ na, const float* __restrict__ nb,
               const float* __restrict__ qsp, int M, int N, int K)
{
    __shared__ __align__(16) float As[16][68];
    __shared__ __align__(16) float Bs[16][68];
    __shared__ __align__(16) float Ts[64][65];
    const int m0 = blockIdx.y * 64, n0 = blockIdx.x * 64;
    const int t = threadIdx.x;
    const int lk = t & 15, lr = t >> 4;
    const int tm = t >> 4, tn = t & 15;
    float acc[4][4] = {};
    for (int k0 = 0; k0 < K; k0 += 16) {
        #pragma unroll
        for (int r = 0; r < 4; r++) {
            As[lk][lr + r*16] = A[(size_t)(m0 + lr + r*16) * K + (k0 + lk)];
            Bs[lk][lr + r*16] = B[(size_t)(n0 + lr + r*16) * K + (k0 + lk)];
        }
        __syncthreads();
        #pragma unroll
        for (int k = 0; k < 16; k++) {
            const float4 a4 = *(const float4*)&As[k][tm*4];
            const float4 b4 = *(const float4*)&Bs[k][tn*4];
            const float av[4] = {a4.x, a4.y, a4.z, a4.w};
            const float bv[4] = {b4.x, b4.y, b4.z, b4.w};
            #pragma unroll
            for (int i = 0; i < 4; i++)
                #pragma unroll
                for (int j = 0; j < 4; j++)
                    acc[i][j] = fmaf(av[i], bv[j], acc[i][j]);
        }
        __syncthreads();
    }
    const float s = qsp[0];   // quantization scale
    float nai[4], nbj[4];
    #pragma unroll
    for (int i = 0; i < 4; i++) nai[i] = na[m0 + tm*4 + i];
    #pragma unroll
    for (int j = 0; j < 4; j++) nbj[j] = nb[n0 + tn*4 + j];
    #pragma unroll
    for (int i = 0; i < 4; i++) {
        u16x4 o;
        #pragma unroll
        for (int j = 0; j < 4; j++) {
            const float c = 0.5f * fmaxf(nai[i] + nbj[j] - 2.0f * acc[i][j], 0.0f);
            o[j] = (unsigned short)quant16(c, s);
            if (CT) Ts[tn*4 + j][tm*4 + i] = c;
        }
        *(u16x4*)&C[(size_t)(m0 + tm*4 + i) * N + n0 + tn*4] = o;
    }
    if (CT) {   // coalesced transposed u16 store via LDS
        __syncthreads();
        const int r = t >> 2, c0 = (t & 3) * 16;
        u16x8 w0, w1;
        #pragma unroll
        for (int e = 0; e < 8; e++) {
            w0[e] = (unsigned short)quant16(Ts[r][c0 + e], s);
            w1[e] = (unsigned short)quant16(Ts[r][c0 + 8 + e], s);
        }
        *(u16x8*)&CT[(size_t)(n0 + r) * M + m0 + c0]     = w0;
        *(u16x8*)&CT[(size_t)(n0 + r) * M + m0 + c0 + 8] = w1;
    }
}

// ---- row squared-norms (D=256 == blockDim) ----
__global__ __launch_bounds__(256)
void row_norm(const float* __restrict__ x, float* __restrict__ o)
{
    const int i = blockIdx.x;
    const float v = x[(size_t)i * DOUT + threadIdx.x];
    float s = wave_sum(v * v);
    __shared__ float red[4];
    const int wid = threadIdx.x >> 6, lane = threadIdx.x & 63;
    if (lane == 0) red[wid] = s;
    __syncthreads();
    if (threadIdx.x == 0) o[i] = red[0] + red[1] + red[2] + red[3];
}

// ---- stage 1: per-column min/max partials ----
__global__ __launch_bounds__(256)
void colminmax_k(const float* __restrict__ xd, const float* __restrict__ x1,
                 const float* __restrict__ x2, float* __restrict__ ws)
{
    const int b = blockIdx.x, c = threadIdx.x;
    const float* src; int r0;
    if (b < 64)      { src = xd; r0 = b * 64; }
    else if (b < 80) { src = x1; r0 = (b - 64) * 64; }
    else             { src = x2; r0 = (b - 80) * 64; }
    float mn = 3.4e38f, mx = -3.4e38f;
    for (int r = 0; r < 64; r++) {
        const float v = src[(size_t)(r0 + r) * DOUT + c];
        mn = fminf(mn, v); mx = fmaxf(mx, v);
    }
    ws[O_PMIN + (ull)b * 256 + c] = mn;
    ws[O_PMAX + (ull)b * 256 + c] = mx;
}

// ---- stage 2: partials -> diam -> eps schedule + quant scale ----
__global__ __launch_bounds__(256)
void eps_k(float* __restrict__ ws)
{
    const int c = threadIdx.x;
    const float* pmin = ws + O_PMIN;
    const float* pmax = ws + O_PMAX;
    float mnd = 3.4e38f, mxd = -3.4e38f;
    float mn1 = 3.4e38f, mx1 = -3.4e38f;
    float mn2 = 3.4e38f, mx2 = -3.4e38f;
    for (int b = 0;  b < 64; b++) { mnd = fminf(mnd, pmin[b*256+c]); mxd = fmaxf(mxd, pmax[b*256+c]); }
    for (int b = 64; b < 80; b++) { mn1 = fminf(mn1, pmin[b*256+c]); mx1 = fmaxf(mx1, pmax[b*256+c]); }
    for (int b = 80; b < 96; b++) { mn2 = fminf(mn2, pmin[b*256+c]); mx2 = fmaxf(mx2, pmax[b*256+c]); }
    const float d1 = fmaxf(mxd, mx1) - fminf(mnd, mn1);
    const float d2 = fmaxf(mxd, mx2) - fminf(mnd, mn2);
    float s1 = wave_sum(d1 * d1);
    float s2 = wave_sum(d2 * d2);
    __shared__ float r1[4], r2[4];
    const int wid = c >> 6, lane = c & 63;
    if (lane == 0) { r1[wid] = s1; r2[wid] = s2; }
    __syncthreads();
    if (c == 0) {   // quantization scale from rigorous bound C <= 0.5*diam^2
        const float d1s = r1[0]+r1[1]+r1[2]+r1[3];
        const float d2s = r2[0]+r2[1]+r2[2]+r2[3];
        const float cb = 0.5f * fmaxf(d1s, d2s) * 1.02f + 1.0f;
        ws[O_QS]     = 65535.0f / cb;   // quant
        ws[O_QS + 1] = cb / 65535.0f;   // dequant
    }
    if (c < 2 * NIT) {
        const int div = c / NIT, tt = c % NIT;
        const float ss = div ? (r2[0]+r2[1]+r2[2]+r2[3]) : (r1[0]+r1[1]+r1[2]+r1[3]);
        const float diam = sqrtf(ss) + 1e-6f;
        const float sc = fmaxf(0.5f, diam * powf(0.8f, (float)tt));
        ws[O_EPS + (ull)div * NIT + tt] = sc * sc;
    }
}

// ---- wave-per-row stable softmin over a u16-quantized row (exp2-scaled) ----
// NC = number of 512-element chunks (row length = NC*512). No barriers.
template<int NC>
__device__ __forceinline__ void softmin_row_q(
    const unsigned short* __restrict__ Crow, const float* __restrict__ hvec,
    float hc2, float eps, float qs,
    const float* __restrict__ selfv, float* __restrict__ outp,
    int row, int phase, int lane)
{
    const float ie2 = LOG2E / eps;
    const float qsc = -qs * ie2;
    const u16x8* Q8 = (const u16x8*)Crow;
    const float4* H4 = (const float4*)hvec;
    float v[NC * 8];
    #pragma unroll
    for (int c = 0; c < NC; c++) {
        const u16x8 q = Q8[c * 64 + lane];
        if (hvec) {
            const float4 ha = H4[c * 128 + lane * 2];
            const float4 hb = H4[c * 128 + lane * 2 + 1];
            const float hv[8] = {ha.x, ha.y, ha.z, ha.w, hb.x, hb.y, hb.z, hb.w};
            #pragma unroll
            for (int e = 0; e < 8; e++)
                v[c*8 + e] = fmaf((float)q[e], qsc, fmaf(hv[e], ie2, hc2));
        } else {
            #pragma unroll
            for (int e = 0; e < 8; e++)
                v[c*8 + e] = fmaf((float)q[e], qsc, hc2);
        }
    }
    float m = v[0];
    #pragma unroll
    for (int k = 1; k < NC * 8; k++) m = fmaxf(m, v[k]);
    m = wave_max(m);
    float s = 0.0f;
    #pragma unroll
    for (int k = 0; k < NC * 8; k++) s += exp2f(v[k] - m);
    s = wave_sum(s);
    if (lane == 0) {
        float res = -eps * LN2 * (m + log2f(s));
        if (phase == 1) res = 0.5f * (selfv[row] + res);
        outp[row] = res;
    }
}

// ---- fused Sinkhorn step: wave-per-row, 4 waves/block, 4096 blocks ----
// wave map (16384 waves):
//  [0,8192)      ft   (C_xy rows, len 1024), div = w>>12
//  [8192,10240)  gt   (C_yx rows, len 4096), div = (w-8192)>>10
//  [10240,14336) f_aa (C_xx rows, len 4096), BOTH divergences (row L1-hot on 2nd pass)
//  [14336,16384) g_bb (C_yy rows, len 1024), div = (w-14336)>>10
__global__ __launch_bounds__(256)
void sinkhorn_phase(float* __restrict__ ws, int phase, int t)
{
    const unsigned short* uq = (const unsigned short*)ws;
    const int wid = threadIdx.x >> 6, lane = threadIdx.x & 63;
    const int w = blockIdx.x * 4 + wid;
    const float qs = ws[O_QS + 1];
    int rb, wb;
    if (phase == 0) { rb = 0; wb = 0; }
    else { rb = t & 1; wb = rb ^ 1; }   // phase 2 passes t=36 -> rb=0

    if (w < 8192) {                       // ft -> f_ab
        const int div = w >> 12, i = w & 4095;
        const float eps = (phase == 2) ? 0.25f : ws[O_EPS + (ull)div * NIT + t];
        const unsigned short* Crow = uq + U_CXY + (ull)div * ND * NS + (ull)i * NS;
        const float* gab_r = ws + O_GAB + ((ull)div * 2 + rb) * NS;
        const float* fab_r = ws + O_FAB + ((ull)div * 2 + rb) * ND;
        float* outp = (phase == 2) ? (ws + O_FABN + (ull)div * ND)
                                   : (ws + O_FAB + ((ull)div * 2 + wb) * ND);
        softmin_row_q<2>(Crow, phase ? gab_r : nullptr, B_LOG2, eps, qs, fab_r, outp, i, phase, lane);
    } else if (w < 10240) {               // gt -> g_ab
        const int q = w - 8192, div = q >> 10, j = q & 1023;
        const float eps = (phase == 2) ? 0.25f : ws[O_EPS + (ull)div * NIT + t];
        const unsigned short* Crow = uq + U_CYX + (ull)div * ND * NS + (ull)j * ND;
        const float* fab_r = ws + O_FAB + ((ull)div * 2 + rb) * ND;
        const float* gab_r = ws + O_GAB + ((ull)div * 2 + rb) * NS;
        float* outp = (phase == 2) ? (ws + O_GABN + (ull)div * NS)
                                   : (ws + O_GAB + ((ull)div * 2 + wb) * NS);
        softmin_row_q<8>(Crow, phase ? fab_r : nullptr, A_LOG2, eps, qs, gab_r, outp, j, phase, lane);
    } else if (w < 14336) {               // f_aa, both divergences sequentially
        const int i = w - 10240;
        const float eps0 = (phase == 2) ? 0.25f : ws[O_EPS + t];
        const float eps1 = (phase == 2) ? 0.25f : ws[O_EPS + NIT + t];
        const unsigned short* Crow = uq + U_CXX + (ull)i * ND;
        const float* faa_r0 = ws + O_FAA + (ull)rb * ND;
        const float* faa_r1 = ws + O_FAA + (2ull + rb) * ND;
        float* out0 = (phase == 2) ? (ws + O_FAAN)      : (ws + O_FAA + (ull)wb * ND);
        float* out1 = (phase == 2) ? (ws + O_FAAN + ND) : (ws + O_FAA + (2ull + wb) * ND);
        softmin_row_q<8>(Crow, phase ? faa_r0 : nullptr, A_LOG2, eps0, qs, faa_r0, out0, i, phase, lane);
        softmin_row_q<8>(Crow, phase ? faa_r1 : nullptr, A_LOG2, eps1, qs, faa_r1, out1, i, phase, lane);
    } else {                              // g_bb
        const int q = w - 14336, div = q >> 10, i = q & 1023;
        const float eps = (phase == 2) ? 0.25f : ws[O_EPS + (ull)div * NIT + t];
        const unsigned short* Crow = uq + U_CYY + (ull)div * NS * NS + (ull)i * NS;
        const float* gbb_r = ws + O_GBB + ((ull)div * 2 + rb) * NS;
        float* outp = (phase == 2) ? (ws + O_GBBN + (ull)div * NS)
                                   : (ws + O_GBB + ((ull)div * 2 + wb) * NS);
        softmin_row_q<2>(Crow, phase ? gbb_r : nullptr, B_LOG2, eps, qs, gbb_r, outp, i, phase, lane);
    }
}

// ---- dist[d] = mean(f_ab_n - f_aa_n) + mean(g_ab_n - g_bb_n) ----
__global__ __launch_bounds__(256)
void reduce_dist(float* __restrict__ ws)
{
    const int d = blockIdx.x;
    const int tix = threadIdx.x;
    float s = 0.0f;
    #pragma unroll
    for (int k = 0; k < 16; k++) {
        const int i = tix + k * 256;
        s += (ws[O_FABN + (ull)d * ND + i] - ws[O_FAAN + (ull)d * ND + i]) * (1.0f / 4096.0f);
    }
    #pragma unroll
    for (int k = 0; k < 4; k++) {
        const int j = tix + k * 256;
        s += (ws[O_GABN + (ull)d * NS + j] - ws[O_GBBN + (ull)d * NS + j]) * (1.0f / 1024.0f);
    }
    s = wave_sum(s);
    __shared__ float red[4];
    const int wid = tix >> 6, lane = tix & 63;
    if (lane == 0) red[wid] = s;
    __syncthreads();
    if (tix == 0) ws[O_DIST + d] = red[0] + red[1] + red[2] + red[3];
}

__global__ void finalize_k(const float* __restrict__ ws, float* __restrict__ out)
{
    const float x = ws[O_DIST + 1] - ws[O_DIST + 0];   // dist2 - dist1
    out[0] = 1.0f / (1.0f + expf(-x));
}

extern "C" void kernel_launch(void* const* d_in, const int* in_sizes, int n_in,
                              void* d_out, int out_size, void* d_ws, size_t ws_size,
                              hipStream_t stream)
{
    if (ws_size < WS_FLOATS * sizeof(float)) return;   // ~77 MB required

    const float* dmat = (const float*)d_in[0];
    const float* s1   = (const float*)d_in[1];
    const float* s2   = (const float*)d_in[2];
    const float* M    = (const float*)d_in[3];
    float* ws  = (float*)d_ws;
    float* out = (float*)d_out;
    unsigned short* uq = (unsigned short*)d_ws;

    float* Mt = ws + O_MT;
    float* xd = ws + O_XD;
    float* x1 = ws + O_X1;
    float* x2 = ws + O_X2;

    transpose_M_k<<<768, 256, 0, stream>>>(M, Mt);
    gemm_proj<<<dim3(4, 64), 256, 0, stream>>>(dmat, Mt, xd, 4096, 256, 768);
    gemm_proj<<<dim3(4, 16), 256, 0, stream>>>(s1,   Mt, x1, 1024, 256, 768);
    gemm_proj<<<dim3(4, 16), 256, 0, stream>>>(s2,   Mt, x2, 1024, 256, 768);
    row_norm<<<4096, 256, 0, stream>>>(xd, ws + O_ND_);
    row_norm<<<1024, 256, 0, stream>>>(x1, ws + O_N1);
    row_norm<<<1024, 256, 0, stream>>>(x2, ws + O_N2);
    // diameter + eps + quant scale BEFORE cost GEMMs (partials overwrite dead Mt)
    colminmax_k<<<96, 256, 0, stream>>>(xd, x1, x2, ws);
    eps_k<<<1, 256, 0, stream>>>(ws);
    // cost matrices, u16-quantized
    const float* qsp = ws + O_QS;
    gemm_cost<<<dim3(64, 64), 256, 0, stream>>>(xd, xd, uq + U_CXX, nullptr, ws + O_ND_, ws + O_ND_, qsp, 4096, 4096, 256);
    gemm_cost<<<dim3(16, 64), 256, 0, stream>>>(xd, x1, uq + U_CXY,           uq + U_CYX,           ws + O_ND_, ws + O_N1, qsp, 4096, 1024, 256);
    gemm_cost<<<dim3(16, 16), 256, 0, stream>>>(x1, x1, uq + U_CYY,           nullptr,              ws + O_N1,  ws + O_N1, qsp, 1024, 1024, 256);
    gemm_cost<<<dim3(16, 64), 256, 0, stream>>>(xd, x2, uq + U_CXY + ND*NS,   uq + U_CYX + ND*NS,   ws + O_ND_, ws + O_N2, qsp, 4096, 1024, 256);
    gemm_cost<<<dim3(16, 16), 256, 0, stream>>>(x2, x2, uq + U_CYY + NS*NS,   nullptr,              ws + O_N2,  ws + O_N2, qsp, 1024, 1024, 256);
    // Sinkhorn loop
    sinkhorn_phase<<<4096, 256, 0, stream>>>(ws, 0, 0);
    for (int t = 0; t < NIT; t++)
        sinkhorn_phase<<<4096, 256, 0, stream>>>(ws, 1, t);
    sinkhorn_phase<<<4096, 256, 0, stream>>>(ws, 2, 36);
    reduce_dist<<<2, 256, 0, stream>>>(ws);
    finalize_k<<<1, 1, 0, stream>>>(ws, out);
}